// Round 1
// baseline (468.725 us; speedup 1.0000x reference)
//
#include <hip/hip_runtime.h>

#define Tq 4096
#define Dq 1024
#define NCOL 2048      // 512 (z) + 512 (zq) + 1024 (v)
#define RIDGEC 1e-3f

typedef float  f4_t  __attribute__((ext_vector_type(4)));
typedef __bf16 bf8_t __attribute__((ext_vector_type(8)));
typedef unsigned short us4_t __attribute__((ext_vector_type(4)));

typedef __attribute__((address_space(1))) const void* gas_t;
typedef __attribute__((address_space(3))) void* sas_t;

__device__ __forceinline__ unsigned short f2bf(float f){
    unsigned int u = __float_as_uint(f);
    u += 0x7fffu + ((u >> 16) & 1u);        // RNE
    return (unsigned short)(u >> 16);
}

// ---------------- convert h -> bf16 ----------------
__global__ __launch_bounds__(256) void k_f2bf(const float* __restrict__ src,
                                              unsigned short* __restrict__ dst){
    size_t i = ((size_t)blockIdx.x*256 + threadIdx.x)*4;
    float4 v = *(const float4*)(src + i);
    us4_t o; o.x=f2bf(v.x); o.y=f2bf(v.y); o.z=f2bf(v.z); o.w=f2bf(v.w);
    *(us4_t*)(dst + i) = o;
}

// ---------------- concat Wk,Wq,Wv -> bf16 (2048 x 1024) ----------------
__global__ __launch_bounds__(256) void k_wcat(const float* __restrict__ Wk,
                                              const float* __restrict__ Wq,
                                              const float* __restrict__ Wv,
                                              unsigned short* __restrict__ dst){
    size_t i = ((size_t)blockIdx.x*256 + threadIdx.x)*4;
    int row = (int)(i >> 10), col = (int)(i & 1023);
    const float* s;
    if (row < 512)       s = Wk + (size_t)row*1024 + col;
    else if (row < 1024) s = Wq + (size_t)(row-512)*1024 + col;
    else                 s = Wv + (size_t)(row-1024)*1024 + col;
    float4 v = *(const float4*)s;
    us4_t o; o.x=f2bf(v.x); o.y=f2bf(v.y); o.z=f2bf(v.z); o.w=f2bf(v.w);
    *(us4_t*)(dst + i) = o;
}

// ---------------- bf16 MFMA GEMM: C(16384x2048 f32) = A(16384x1024) * W^T(2048x1024) ----------------
__global__ __launch_bounds__(256) void k_gemm(const unsigned short* __restrict__ A,
                                              const unsigned short* __restrict__ Bw,
                                              float* __restrict__ C){
    __shared__ __align__(16) unsigned short As[128*32];
    __shared__ __align__(16) unsigned short Bs[128*32];
    const int tid = threadIdx.x, w = tid >> 6, lane = tid & 63;
    const int m0 = blockIdx.y*128, n0 = blockIdx.x*128;
    const int wm = (w >> 1)*64, wn = (w & 1)*64;
    const int row16 = lane & 15, klo = (lane >> 4)*8;

    f4_t acc[4][4];
#pragma unroll
    for (int i=0;i<4;++i)
#pragma unroll
        for (int j=0;j<4;++j) acc[i][j] = (f4_t){0.f,0.f,0.f,0.f};

    for (int k0 = 0; k0 < Dq; k0 += 32){
#pragma unroll
        for (int j=0;j<2;++j){
            int chunk = w*2 + j;
            int e = chunk*512 + lane*8;
            int r = e >> 5, c = e & 31;
            const unsigned short* ga = A  + (size_t)(m0 + r)*Dq + k0 + c;
            const unsigned short* gb = Bw + (size_t)(n0 + r)*Dq + k0 + c;
            __builtin_amdgcn_global_load_lds((gas_t)ga, (sas_t)&As[chunk*512], 16, 0, 0);
            __builtin_amdgcn_global_load_lds((gas_t)gb, (sas_t)&Bs[chunk*512], 16, 0, 0);
        }
        __syncthreads();
        bf8_t aF[4], bF[4];
#pragma unroll
        for (int i=0;i<4;++i) aF[i] = *(const bf8_t*)&As[(wm + i*16 + row16)*32 + klo];
#pragma unroll
        for (int j=0;j<4;++j) bF[j] = *(const bf8_t*)&Bs[(wn + j*16 + row16)*32 + klo];
#pragma unroll
        for (int i=0;i<4;++i)
#pragma unroll
            for (int j=0;j<4;++j)
                acc[i][j] = __builtin_amdgcn_mfma_f32_16x16x32_bf16(aF[i], bF[j], acc[i][j], 0, 0, 0);
        __syncthreads();
    }
#pragma unroll
    for (int i=0;i<4;++i){
#pragma unroll
        for (int j=0;j<4;++j){
            int col = n0 + wn + j*16 + row16;
            int rb  = m0 + wm + i*16 + (lane >> 4)*4;
#pragma unroll
            for (int q=0;q<4;++q)
                C[(size_t)(rb+q)*NCOL + col] = acc[i][j][q];
        }
    }
}

// ---------------- per-(b,h) max ||z_t|| ----------------
__global__ __launch_bounds__(256) void k_norm(const float* __restrict__ zqv,
                                              float* __restrict__ mn){
    const int bh = blockIdx.x, b = bh >> 4, h = bh & 15;
    const float* base = zqv + (size_t)b*Tq*NCOL + h*32;
    float mx = 0.f;
    for (int t = threadIdx.x; t < Tq; t += 256){
        const float4* p = (const float4*)(base + (size_t)t*NCOL);
        float s = 0.f;
#pragma unroll
        for (int q=0;q<8;++q){ float4 v = p[q]; s += v.x*v.x + v.y*v.y + v.z*v.z + v.w*v.w; }
        mx = fmaxf(mx, s);
    }
#pragma unroll
    for (int off=32; off; off >>= 1) mx = fmaxf(mx, __shfl_down(mx, off, 64));
    __shared__ float red[4];
    if ((threadIdx.x & 63) == 0) red[threadIdx.x >> 6] = mx;
    __syncthreads();
    if (threadIdx.x == 0){
        float m = fmaxf(fmaxf(red[0], red[1]), fmaxf(red[2], red[3]));
        mn[bh] = fmaxf(sqrtf(m), 1e-6f);
    }
}

// ---------------- G / M_cov / C_v raw partial sums (8 t-chunks) ----------------
__global__ __launch_bounds__(256) void k_cov(const float* __restrict__ zqv,
                                             const float* __restrict__ mask,
                                             float* __restrict__ part){
    __shared__ float Zs[65*32];
    __shared__ float Vs[64*64];
    __shared__ float Msk[65];
    const int tid = threadIdx.x;
    const int c = blockIdx.x, bh = blockIdx.y, b = bh >> 4, h = bh & 15;
    const float* zbase = zqv + (size_t)b*Tq*NCOL + h*32;
    const float* vbase = zqv + (size_t)b*Tq*NCOL + 1024 + h*64;
    const float* mbase = mask + (size_t)b*Tq;
    const int rg = tid >> 3, s0 = (tid & 7)*4;
    const int p  = tid >> 2, r0 = (tid & 3)*8;
    float ag[4] = {0,0,0,0}, am[4] = {0,0,0,0}, ac[8] = {0,0,0,0,0,0,0,0};

    for (int t0 = c*512; t0 < c*512 + 512; t0 += 64){
        __syncthreads();
        for (int i = tid; i < 65*32; i += 256){
            int rr = i >> 5, cc = i & 31, t = t0 - 1 + rr;
            Zs[i] = (t >= 0) ? zbase[(size_t)t*NCOL + cc] : 0.f;
        }
        for (int i = tid; i < 64*64; i += 256){
            int rr = i >> 6, cc = i & 63;
            Vs[i] = vbase[(size_t)(t0 + rr)*NCOL + cc];
        }
        if (tid < 65){ int t = t0 - 1 + tid; Msk[tid] = (t >= 0) ? mbase[t] : 0.f; }
        __syncthreads();
#pragma unroll 2
        for (int tt = 0; tt < 64; ++tt){
            const float mt = Msk[tt+1], mprev = Msk[tt];
            const float m2 = mt*mt;
            const float al = mt*mprev, a2 = al*al;
            const float* zr_ = &Zs[(tt+1)*32];
            const float* zp_ = &Zs[tt*32];
            const float zr = zr_[rg];
            const float4 zs4 = *(const float4*)(zr_ + s0);
            const float4 zp4 = *(const float4*)(zp_ + s0);
            const float zg = zr*m2, zm = zr*a2;
            ag[0] += zg*zs4.x; ag[1] += zg*zs4.y; ag[2] += zg*zs4.z; ag[3] += zg*zs4.w;
            am[0] += zm*zp4.x; am[1] += zm*zp4.y; am[2] += zm*zp4.z; am[3] += zm*zp4.w;
            const float vp = Vs[tt*64 + p]*m2;
            const float4 za = *(const float4*)(zr_ + r0);
            const float4 zb = *(const float4*)(zr_ + r0 + 4);
            ac[0] += vp*za.x; ac[1] += vp*za.y; ac[2] += vp*za.z; ac[3] += vp*za.w;
            ac[4] += vp*zb.x; ac[5] += vp*zb.y; ac[6] += vp*zb.z; ac[7] += vp*zb.w;
        }
    }
    float* dst = part + ((size_t)c*64 + bh)*4096;
#pragma unroll
    for (int q=0;q<4;++q){ dst[tid*4+q] = ag[q]; dst[1024 + tid*4+q] = am[q]; }
#pragma unroll
    for (int q=0;q<8;++q) dst[2048 + tid*8+q] = ac[q];
}

// ---------------- per-(b,h) fp32 solver: Cholesky, Linv, power-iter, E = (eta/mn) C G^-1 L A^2 L^-1 ----------------
__global__ __launch_bounds__(256) void k_solve(const float* __restrict__ part,
                                               const float* __restrict__ mnbuf,
                                               const float* __restrict__ eta_p,
                                               const float* __restrict__ gam_p,
                                               float* __restrict__ Ebuf){
    __shared__ float sG[1024], sM[1024], sC[2048], sL[1024], sLi[1024], sT1[1024], sT2[1024];
    __shared__ float sv[32], su[32], sw[32], ssc[4];
    const int tid = threadIdx.x, bh = blockIdx.x;
    const float mn = mnbuf[bh];
    const float i1 = 1.f/mn, i2 = i1*i1;
    const size_t pb = (size_t)bh*4096;

    for (int i = tid; i < 1024; i += 256){
        float a0 = 0.f, a1 = 0.f;
        for (int c = 0; c < 8; ++c){
            const float* p = part + ((size_t)c*64)*4096 + pb;
            a0 += p[i]; a1 += p[1024 + i];
        }
        sT1[i] = a0*i2; sM[i] = a1*i2;
    }
    for (int i = tid; i < 2048; i += 256){
        float a = 0.f;
        for (int c = 0; c < 8; ++c) a += part[((size_t)c*64)*4096 + pb + 2048 + i];
        sC[i] = a*i1;
    }
    __syncthreads();
    for (int i = tid; i < 1024; i += 256){
        int r = i >> 5, s = i & 31;
        sG[i] = 0.5f*(sT1[i] + sT1[s*32 + r]) + (r == s ? RIDGEC : 0.f);
    }
    __syncthreads();
    // Cholesky (lower) in place on sG
    for (int j = 0; j < 32; ++j){
        if (tid == 0) sG[j*32 + j] = sqrtf(sG[j*32 + j]);
        __syncthreads();
        if (tid > j && tid < 32) sG[tid*32 + j] /= sG[j*32 + j];
        __syncthreads();
        for (int e = tid; e < 1024; e += 256){
            int r = e >> 5, s = e & 31;
            if (r > j && s > j && s <= r) sG[e] -= sG[r*32 + j]*sG[s*32 + j];
        }
        __syncthreads();
    }
    for (int i = tid; i < 1024; i += 256){ int r = i >> 5, s = i & 31; sL[i] = (s <= r) ? sG[i] : 0.f; }
    __syncthreads();
    // Linv by forward substitution (one column per thread)
    if (tid < 32){
        int c = tid;
        for (int i = 0; i < 32; ++i){
            float x = 0.f;
            if (i >= c){
                x = (i == c) ? 1.f : 0.f;
                for (int k = c; k < i; ++k) x -= sL[i*32 + k]*sLi[k*32 + c];
                x /= sL[i*32 + i];
            }
            sLi[i*32 + c] = x;
        }
    }
    __syncthreads();
    // T1 = Li @ M ; T2 = T1 @ Li^T  (= A_w pre-scale)
    for (int i = tid; i < 1024; i += 256){ int r = i>>5, s = i&31; float a = 0.f;
        for (int k = 0; k < 32; ++k) a += sLi[r*32+k]*sM[k*32+s]; sT1[i] = a; }
    __syncthreads();
    for (int i = tid; i < 1024; i += 256){ int r = i>>5, s = i&31; float a = 0.f;
        for (int k = 0; k < 32; ++k) a += sT1[r*32+k]*sLi[s*32+k]; sT2[i] = a; }
    __syncthreads();
    // power iteration (6 iters)
    if (tid < 32) sv[tid] = 0.17677669529663687f;
    __syncthreads();
    for (int it = 0; it < 6; ++it){
        if (tid < 32){ float a = 0.f; for (int k = 0; k < 32; ++k) a += sT2[tid*32+k]*sv[k]; su[tid] = a; }
        __syncthreads();
        if (tid == 0){ float a = 0.f; for (int k = 0; k < 32; ++k) a += su[k]*su[k]; ssc[0] = 1.f/fmaxf(sqrtf(a), 1e-8f); }
        __syncthreads();
        if (tid < 32) su[tid] *= ssc[0];
        __syncthreads();
        if (tid < 32){ float a = 0.f; for (int k = 0; k < 32; ++k) a += sT2[k*32+tid]*su[k]; sw[tid] = a; }
        __syncthreads();
        if (tid == 0){ float a = 0.f; for (int k = 0; k < 32; ++k) a += sw[k]*sw[k]; ssc[0] = 1.f/fmaxf(sqrtf(a), 1e-8f); }
        __syncthreads();
        if (tid < 32) sv[tid] = sw[tid]*ssc[0];
        __syncthreads();
    }
    if (tid == 0){
        float a = 0.f;
        for (int r = 0; r < 32; ++r){ float t = 0.f; for (int k = 0; k < 32; ++k) t += sT2[r*32+k]*sv[k]; a += t*t; }
        float sigma = sqrtf(a);
        float gam = fminf(fmaxf(gam_p[0], 1.f), 1.5f);
        ssc[1] = gam/fmaxf(sigma, 1.f);
        ssc[2] = eta_p[0]*i1;
    }
    __syncthreads();
    for (int i = tid; i < 1024; i += 256) sT1[i] = sT2[i]*ssc[1];          // Aw
    __syncthreads();
    for (int i = tid; i < 1024; i += 256){ int r = i>>5, s = i&31; float a = 0.f;
        for (int k = 0; k < 32; ++k) a += sT1[r*32+k]*sT1[k*32+s]; sT2[i] = a; }   // A2
    __syncthreads();
    for (int i = tid; i < 1024; i += 256){ int r = i>>5, s = i&31; float a = 0.f;
        for (int k = 0; k < 32; ++k) a += sL[r*32+k]*sT2[k*32+s]; sM[i] = a; }     // L@A2
    __syncthreads();
    for (int i = tid; i < 1024; i += 256){ int r = i>>5, s = i&31; float a = 0.f;
        for (int k = 0; k < 32; ++k) a += sM[r*32+k]*sLi[k*32+s]; sT2[i] = a; }    // (L@A2)@Li
    __syncthreads();
    for (int i = tid; i < 1024; i += 256){ int r = i>>5, s = i&31; float a = 0.f;
        for (int k = 0; k < 32; ++k) a += sLi[k*32+r]*sLi[k*32+s]; sT1[i] = a; }   // Gi = Li^T Li
    __syncthreads();
    for (int i = tid; i < 1024; i += 256){ int r = i>>5, s = i&31; float a = 0.f;
        for (int k = 0; k < 32; ++k) a += sT1[r*32+k]*sT2[k*32+s]; sM[i] = a; }    // F = Gi@(L A2 Li)
    __syncthreads();
    const float esc = ssc[2];
    for (int i = tid; i < 2048; i += 256){ int p = i>>5, s = i&31; float a = 0.f;
        for (int k = 0; k < 32; ++k) a += sC[p*32+k]*sM[k*32+s];
        Ebuf[(size_t)bh*2048 + i] = a*esc; }
}

// ---------------- out[b,t,h,:] = E[b,h] @ zq[b,t,h,:] ----------------
__global__ __launch_bounds__(256) void k_out(const float* __restrict__ zqv,
                                             const float* __restrict__ Ebuf,
                                             float* __restrict__ out){
    __shared__ float Es[2048];
    const int bh = blockIdx.y, b = bh >> 4, h = bh & 15;
    const int t0 = blockIdx.x*128;
    for (int i = threadIdx.x; i < 2048; i += 256) Es[i] = Ebuf[(size_t)bh*2048 + i];
    __syncthreads();
    const int t = t0 + (threadIdx.x >> 1);
    const int p0 = (threadIdx.x & 1)*32;
    const float* zq = zqv + ((size_t)b*Tq + t)*NCOL + 512 + h*32;
    float4 z4[8];
#pragma unroll
    for (int q=0;q<8;++q) z4[q] = ((const float4*)zq)[q];
    float* o = out + ((size_t)b*Tq + t)*1024 + h*64 + p0;
#pragma unroll
    for (int pp = 0; pp < 32; pp += 4){
        float4 res;
        float* rp = (float*)&res;
#pragma unroll
        for (int s = 0; s < 4; ++s){
            const float4* er = (const float4*)&Es[(p0 + pp + s)*32];
            float a = 0.f;
#pragma unroll
            for (int q = 0; q < 8; ++q){
                float4 e = er[q];
                a += e.x*z4[q].x + e.y*z4[q].y + e.z*z4[q].z + e.w*z4[q].w;
            }
            rp[s] = a;
        }
        *(float4*)(o + pp) = res;
    }
}

extern "C" void kernel_launch(void* const* d_in, const int* in_sizes, int n_in,
                              void* d_out, int out_size, void* d_ws, size_t ws_size,
                              hipStream_t stream) {
    const float* h    = (const float*)d_in[0];
    const float* mask = (const float*)d_in[1];
    const float* Wk   = (const float*)d_in[2];
    const float* Wq   = (const float*)d_in[3];
    const float* Wv   = (const float*)d_in[4];
    const float* eta  = (const float*)d_in[5];
    const float* gam  = (const float*)d_in[6];
    float* out = (float*)d_out;

    char* ws = (char*)d_ws;
    unsigned short* hbf = (unsigned short*)(ws);                       // 33,554,432 B
    unsigned short* wbf = (unsigned short*)(ws + 33554432);            //  4,194,304 B
    float* zqv  = (float*)(ws + 37748736);                             // 134,217,728 B
    float* mn   = (float*)(ws + 171966464);                            //        256 B
    float* part = (float*)(ws + 171966720);                            //  8,388,608 B
    float* Ebuf = (float*)(ws + 180355328);                            //    524,288 B

    k_f2bf <<<16384, 256, 0, stream>>>(h, hbf);
    k_wcat <<<2048,  256, 0, stream>>>(Wk, Wq, Wv, wbf);
    k_gemm <<<dim3(16, 128), 256, 0, stream>>>(hbf, wbf, zqv);
    k_norm <<<64,    256, 0, stream>>>(zqv, mn);
    k_cov  <<<dim3(8, 64), 256, 0, stream>>>(zqv, mask, part);
    k_solve<<<64,    256, 0, stream>>>(part, mn, eta, gam, Ebuf);
    k_out  <<<dim3(32, 64), 256, 0, stream>>>(zqv, Ebuf, out);
}

// Round 2
// 419.724 us; speedup vs baseline: 1.1167x; 1.1167x over previous
//
#include <hip/hip_runtime.h>

#define Tq 4096
#define Dq 1024
#define NCOL 2048      // 512 (z) + 512 (zq) + 1024 (v)
#define RIDGEC 1e-3f

typedef float  f4_t  __attribute__((ext_vector_type(4)));
typedef __bf16 bf8_t __attribute__((ext_vector_type(8)));
typedef unsigned short us4_t __attribute__((ext_vector_type(4)));

typedef __attribute__((address_space(1))) const void* gas_t;
typedef __attribute__((address_space(3))) void* sas_t;

__device__ __forceinline__ unsigned short f2bf(float f){
    unsigned int u = __float_as_uint(f);
    u += 0x7fffu + ((u >> 16) & 1u);        // RNE
    return (unsigned short)(u >> 16);
}
__device__ __forceinline__ float bf2f(unsigned short u){
    return __uint_as_float(((unsigned int)u) << 16);
}

// ---------------- convert h -> bf16 ----------------
__global__ __launch_bounds__(256) void k_f2bf(const float* __restrict__ src,
                                              unsigned short* __restrict__ dst){
    size_t i = ((size_t)blockIdx.x*256 + threadIdx.x)*4;
    float4 v = *(const float4*)(src + i);
    us4_t o; o.x=f2bf(v.x); o.y=f2bf(v.y); o.z=f2bf(v.z); o.w=f2bf(v.w);
    *(us4_t*)(dst + i) = o;
}

// ---------------- concat Wk,Wq,Wv -> bf16 (2048 x 1024) ----------------
__global__ __launch_bounds__(256) void k_wcat(const float* __restrict__ Wk,
                                              const float* __restrict__ Wq,
                                              const float* __restrict__ Wv,
                                              unsigned short* __restrict__ dst){
    size_t i = ((size_t)blockIdx.x*256 + threadIdx.x)*4;
    int row = (int)(i >> 10), col = (int)(i & 1023);
    const float* s;
    if (row < 512)       s = Wk + (size_t)row*1024 + col;
    else if (row < 1024) s = Wq + (size_t)(row-512)*1024 + col;
    else                 s = Wv + (size_t)(row-1024)*1024 + col;
    float4 v = *(const float4*)s;
    us4_t o; o.x=f2bf(v.x); o.y=f2bf(v.y); o.z=f2bf(v.z); o.w=f2bf(v.w);
    *(us4_t*)(dst + i) = o;
}

// ---------------- bf16 MFMA GEMM: [z|zq|v] = h @ W^T ; z,v out bf16, zq out f32 ----------------
__global__ __launch_bounds__(256) void k_gemm(const unsigned short* __restrict__ A,
                                              const unsigned short* __restrict__ Bw,
                                              unsigned short* __restrict__ zbf,
                                              float* __restrict__ zqf,
                                              unsigned short* __restrict__ vbf){
    __shared__ __align__(16) unsigned short As[128*32];
    __shared__ __align__(16) unsigned short Bs[128*32];
    const int tid = threadIdx.x, w = tid >> 6, lane = tid & 63;
    const int m0 = blockIdx.y*128, n0 = blockIdx.x*128;
    const int wm = (w >> 1)*64, wn = (w & 1)*64;
    const int row16 = lane & 15, klo = (lane >> 4)*8;

    f4_t acc[4][4];
#pragma unroll
    for (int i=0;i<4;++i)
#pragma unroll
        for (int j=0;j<4;++j) acc[i][j] = (f4_t){0.f,0.f,0.f,0.f};

    for (int k0 = 0; k0 < Dq; k0 += 32){
#pragma unroll
        for (int j=0;j<2;++j){
            int chunk = w*2 + j;
            int e = chunk*512 + lane*8;
            int r = e >> 5, c = e & 31;
            const unsigned short* ga = A  + (size_t)(m0 + r)*Dq + k0 + c;
            const unsigned short* gb = Bw + (size_t)(n0 + r)*Dq + k0 + c;
            __builtin_amdgcn_global_load_lds((gas_t)ga, (sas_t)&As[chunk*512], 16, 0, 0);
            __builtin_amdgcn_global_load_lds((gas_t)gb, (sas_t)&Bs[chunk*512], 16, 0, 0);
        }
        __syncthreads();
        bf8_t aF[4], bF[4];
#pragma unroll
        for (int i=0;i<4;++i) aF[i] = *(const bf8_t*)&As[(wm + i*16 + row16)*32 + klo];
#pragma unroll
        for (int j=0;j<4;++j) bF[j] = *(const bf8_t*)&Bs[(wn + j*16 + row16)*32 + klo];
#pragma unroll
        for (int i=0;i<4;++i)
#pragma unroll
            for (int j=0;j<4;++j)
                acc[i][j] = __builtin_amdgcn_mfma_f32_16x16x32_bf16(aF[i], bF[j], acc[i][j], 0, 0, 0);
        __syncthreads();
    }
    const int region = n0 >> 9;   // 0:z  1:zq  2,3:v
#pragma unroll
    for (int i=0;i<4;++i){
#pragma unroll
        for (int j=0;j<4;++j){
            int col = n0 + wn + j*16 + row16;
            int rb  = m0 + wm + i*16 + (lane >> 4)*4;
            if (region == 0){
#pragma unroll
                for (int q=0;q<4;++q) zbf[(size_t)(rb+q)*512 + col] = f2bf(acc[i][j][q]);
            } else if (region == 1){
#pragma unroll
                for (int q=0;q<4;++q) zqf[(size_t)(rb+q)*512 + (col-512)] = acc[i][j][q];
            } else {
#pragma unroll
                for (int q=0;q<4;++q) vbf[(size_t)(rb+q)*1024 + (col-1024)] = f2bf(acc[i][j][q]);
            }
        }
    }
}

// ---------------- init mn ----------------
__global__ void k_init(unsigned int* mn){ mn[threadIdx.x] = 0u; }

// ---------------- per-(b,h) max ||z_t||^2 (atomicMax on float bits, nonneg) ----------------
__global__ __launch_bounds__(256) void k_norm(const unsigned short* __restrict__ zbf,
                                              unsigned int* __restrict__ mn){
    const int c = blockIdx.x, bh = blockIdx.y, b = bh >> 4, h = bh & 15;
    const unsigned short* zb = zbf + (size_t)b*Tq*512 + h*32;
    float mx = 0.f;
    for (int t = c*512 + threadIdx.x; t < c*512 + 512; t += 256){
        const us4_t* p = (const us4_t*)(zb + (size_t)t*512);
        float s = 0.f;
#pragma unroll
        for (int q=0;q<8;++q){
            us4_t u = p[q];
            float a=bf2f(u.x), b2=bf2f(u.y), c2=bf2f(u.z), d2=bf2f(u.w);
            s += a*a + b2*b2 + c2*c2 + d2*d2;
        }
        mx = fmaxf(mx, s);
    }
#pragma unroll
    for (int off=32; off; off >>= 1) mx = fmaxf(mx, __shfl_down(mx, off, 64));
    __shared__ float red[4];
    if ((threadIdx.x & 63) == 0) red[threadIdx.x >> 6] = mx;
    __syncthreads();
    if (threadIdx.x == 0){
        float m = fmaxf(fmaxf(red[0], red[1]), fmaxf(red[2], red[3]));
        atomicMax(mn + bh, __float_as_uint(m));
    }
}

// ---------------- G / M_cov / C_v partial sums: register-blocked 8x8 outer products ----------------
// roles per lane: 0-15 G patch, 16-31 M patch, 32-63 C patch; wave w handles tt = w mod 4
__global__ __launch_bounds__(256) void k_cov(const unsigned short* __restrict__ zbf,
                                             const unsigned short* __restrict__ vbf,
                                             const float* __restrict__ mask,
                                             float* __restrict__ part){
    __shared__ float Zs[65*32];
    __shared__ float Vs[64*64];
    __shared__ float Msk[66];
    const int tid = threadIdx.x, w = tid >> 6, lane = tid & 63;
    const int c = blockIdx.x, bh = blockIdx.y, b = bh >> 4, h = bh & 15;
    const unsigned short* zb = zbf + (size_t)b*Tq*512 + h*32;
    const unsigned short* vb = vbf + (size_t)b*Tq*1024 + h*64;
    const float* mb = mask + (size_t)b*Tq;

    const bool isC = lane >= 32;
    const bool isM = (lane >= 16) && (lane < 32);
    const int li = isC ? (lane - 32) : (lane & 15);
    const int i0 = (li >> 2)*8, j0 = (li & 3)*8;
    const float* Xb = isC ? (Vs + i0) : (Zs + 32 + i0);
    const int xst = isC ? 64 : 32;
    const float* Yb = isM ? (Zs + j0) : (Zs + 32 + j0);
    const int slotbase = isC ? (2048 + i0*32 + j0) : ((isM ? 1024 : 0) + i0*32 + j0);

    float acc[8][8];
#pragma unroll
    for (int i=0;i<8;++i)
#pragma unroll
        for (int j=0;j<8;++j) acc[i][j] = 0.f;

    for (int t0 = c*512; t0 < c*512 + 512; t0 += 64){
        __syncthreads();
        for (int i = tid; i < 520; i += 256){
            int r = i >> 3, cc = (i & 7)*4;
            int t = t0 - 1 + r;
            float4 o;
            if (t >= 0){
                us4_t u = *(const us4_t*)(zb + (size_t)t*512 + cc);
                o.x = bf2f(u.x); o.y = bf2f(u.y); o.z = bf2f(u.z); o.w = bf2f(u.w);
            } else { o.x=0.f; o.y=0.f; o.z=0.f; o.w=0.f; }
            *(float4*)&Zs[r*32 + cc] = o;
        }
        for (int i = tid; i < 1024; i += 256){
            int rr = i >> 4, cc = (i & 15)*4;
            us4_t u = *(const us4_t*)(vb + (size_t)(t0 + rr)*1024 + cc);
            float4 o; o.x=bf2f(u.x); o.y=bf2f(u.y); o.z=bf2f(u.z); o.w=bf2f(u.w);
            *(float4*)&Vs[rr*64 + cc] = o;
        }
        if (tid < 65){ int t = t0 - 1 + tid; Msk[tid] = (t >= 0) ? mb[t] : 0.f; }
        __syncthreads();
#pragma unroll 2
        for (int tt = w; tt < 64; tt += 4){
            const float mt = Msk[tt+1], mp = Msk[tt];
            const float m2 = mt*mt, al = mt*mp;
            const float wgt = isM ? (al*al) : m2;
            const float* xp = Xb + tt*xst;
            const float* yp = Yb + tt*32;
            float4 x0 = *(const float4*)xp, x1 = *(const float4*)(xp + 4);
            float4 y0 = *(const float4*)yp, y1 = *(const float4*)(yp + 4);
            float xs[8] = {x0.x*wgt, x0.y*wgt, x0.z*wgt, x0.w*wgt,
                           x1.x*wgt, x1.y*wgt, x1.z*wgt, x1.w*wgt};
            float ys[8] = {y0.x, y0.y, y0.z, y0.w, y1.x, y1.y, y1.z, y1.w};
#pragma unroll
            for (int i=0;i<8;++i)
#pragma unroll
                for (int j=0;j<8;++j) acc[i][j] += xs[i]*ys[j];
        }
    }
    // cross-wave reduce in LDS (reuse Vs: 4096 floats)
    float* Acc = Vs;
    __syncthreads();
#pragma unroll
    for (int r = 0; r < 4; ++r){
        if (w == r){
            if (r == 0){
#pragma unroll
                for (int i=0;i<8;++i)
#pragma unroll
                    for (int j=0;j<8;++j) Acc[slotbase + i*32 + j] = acc[i][j];
            } else {
#pragma unroll
                for (int i=0;i<8;++i)
#pragma unroll
                    for (int j=0;j<8;++j) Acc[slotbase + i*32 + j] += acc[i][j];
            }
        }
        __syncthreads();
    }
    float* dst = part + ((size_t)c*64 + bh)*4096;
    for (int i = tid; i < 4096; i += 256) dst[i] = Acc[i];
}

// ---------------- per-(b,h) fp32 solver ----------------
__global__ __launch_bounds__(256) void k_solve(const float* __restrict__ part,
                                               const float* __restrict__ mnbuf,
                                               const float* __restrict__ eta_p,
                                               const float* __restrict__ gam_p,
                                               float* __restrict__ Ebuf){
    __shared__ float sG[1024], sM[1024], sC[2048], sL[1024], sLi[1024], sT1[1024], sT2[1024];
    __shared__ float sv[32], su[32], sw[32], ssc[4];
    const int tid = threadIdx.x, bh = blockIdx.x;
    const float mn = fmaxf(sqrtf(mnbuf[bh]), 1e-6f);
    const float i1 = 1.f/mn, i2 = i1*i1;
    const size_t pb = (size_t)bh*4096;

    for (int i = tid; i < 1024; i += 256){
        float a0 = 0.f, a1 = 0.f;
        for (int c = 0; c < 8; ++c){
            const float* p = part + ((size_t)c*64)*4096 + pb;
            a0 += p[i]; a1 += p[1024 + i];
        }
        sT1[i] = a0*i2; sM[i] = a1*i2;
    }
    for (int i = tid; i < 2048; i += 256){
        float a = 0.f;
        for (int c = 0; c < 8; ++c) a += part[((size_t)c*64)*4096 + pb + 2048 + i];
        sC[i] = a*i1;
    }
    __syncthreads();
    for (int i = tid; i < 1024; i += 256){
        int r = i >> 5, s = i & 31;
        sG[i] = 0.5f*(sT1[i] + sT1[s*32 + r]) + (r == s ? RIDGEC : 0.f);
    }
    __syncthreads();
    // Cholesky (lower) in place on sG
    for (int j = 0; j < 32; ++j){
        if (tid == 0) sG[j*32 + j] = sqrtf(sG[j*32 + j]);
        __syncthreads();
        if (tid > j && tid < 32) sG[tid*32 + j] /= sG[j*32 + j];
        __syncthreads();
        for (int e = tid; e < 1024; e += 256){
            int r = e >> 5, s = e & 31;
            if (r > j && s > j && s <= r) sG[e] -= sG[r*32 + j]*sG[s*32 + j];
        }
        __syncthreads();
    }
    for (int i = tid; i < 1024; i += 256){ int r = i >> 5, s = i & 31; sL[i] = (s <= r) ? sG[i] : 0.f; }
    __syncthreads();
    // Linv by forward substitution (one column per thread)
    if (tid < 32){
        int c = tid;
        for (int i = 0; i < 32; ++i){
            float x = 0.f;
            if (i >= c){
                x = (i == c) ? 1.f : 0.f;
                for (int k = c; k < i; ++k) x -= sL[i*32 + k]*sLi[k*32 + c];
                x /= sL[i*32 + i];
            }
            sLi[i*32 + c] = x;
        }
    }
    __syncthreads();
    for (int i = tid; i < 1024; i += 256){ int r = i>>5, s = i&31; float a = 0.f;
        for (int k = 0; k < 32; ++k) a += sLi[r*32+k]*sM[k*32+s]; sT1[i] = a; }
    __syncthreads();
    for (int i = tid; i < 1024; i += 256){ int r = i>>5, s = i&31; float a = 0.f;
        for (int k = 0; k < 32; ++k) a += sT1[r*32+k]*sLi[s*32+k]; sT2[i] = a; }
    __syncthreads();
    if (tid < 32) sv[tid] = 0.17677669529663687f;
    __syncthreads();
    for (int it = 0; it < 6; ++it){
        if (tid < 32){ float a = 0.f; for (int k = 0; k < 32; ++k) a += sT2[tid*32+k]*sv[k]; su[tid] = a; }
        __syncthreads();
        if (tid == 0){ float a = 0.f; for (int k = 0; k < 32; ++k) a += su[k]*su[k]; ssc[0] = 1.f/fmaxf(sqrtf(a), 1e-8f); }
        __syncthreads();
        if (tid < 32) su[tid] *= ssc[0];
        __syncthreads();
        if (tid < 32){ float a = 0.f; for (int k = 0; k < 32; ++k) a += sT2[k*32+tid]*su[k]; sw[tid] = a; }
        __syncthreads();
        if (tid == 0){ float a = 0.f; for (int k = 0; k < 32; ++k) a += sw[k]*sw[k]; ssc[0] = 1.f/fmaxf(sqrtf(a), 1e-8f); }
        __syncthreads();
        if (tid < 32) sv[tid] = sw[tid]*ssc[0];
        __syncthreads();
    }
    if (tid == 0){
        float a = 0.f;
        for (int r = 0; r < 32; ++r){ float t = 0.f; for (int k = 0; k < 32; ++k) t += sT2[r*32+k]*sv[k]; a += t*t; }
        float sigma = sqrtf(a);
        float gam = fminf(fmaxf(gam_p[0], 1.f), 1.5f);
        ssc[1] = gam/fmaxf(sigma, 1.f);
        ssc[2] = eta_p[0]*i1;
    }
    __syncthreads();
    for (int i = tid; i < 1024; i += 256) sT1[i] = sT2[i]*ssc[1];          // Aw
    __syncthreads();
    for (int i = tid; i < 1024; i += 256){ int r = i>>5, s = i&31; float a = 0.f;
        for (int k = 0; k < 32; ++k) a += sT1[r*32+k]*sT1[k*32+s]; sT2[i] = a; }   // A2
    __syncthreads();
    for (int i = tid; i < 1024; i += 256){ int r = i>>5, s = i&31; float a = 0.f;
        for (int k = 0; k < 32; ++k) a += sL[r*32+k]*sT2[k*32+s]; sM[i] = a; }     // L@A2
    __syncthreads();
    for (int i = tid; i < 1024; i += 256){ int r = i>>5, s = i&31; float a = 0.f;
        for (int k = 0; k < 32; ++k) a += sM[r*32+k]*sLi[k*32+s]; sT2[i] = a; }    // (L@A2)@Li
    __syncthreads();
    for (int i = tid; i < 1024; i += 256){ int r = i>>5, s = i&31; float a = 0.f;
        for (int k = 0; k < 32; ++k) a += sLi[k*32+r]*sLi[k*32+s]; sT1[i] = a; }   // Gi = Li^T Li
    __syncthreads();
    for (int i = tid; i < 1024; i += 256){ int r = i>>5, s = i&31; float a = 0.f;
        for (int k = 0; k < 32; ++k) a += sT1[r*32+k]*sT2[k*32+s]; sM[i] = a; }    // F
    __syncthreads();
    const float esc = ssc[2];
    for (int i = tid; i < 2048; i += 256){ int p = i>>5, s = i&31; float a = 0.f;
        for (int k = 0; k < 32; ++k) a += sC[p*32+k]*sM[k*32+s];
        Ebuf[(size_t)bh*2048 + i] = a*esc; }
}

// ---------------- out[b,t,h,:] = E[b,h] @ zq[b,t,h,:] ----------------
__global__ __launch_bounds__(256) void k_out(const float* __restrict__ zqf,
                                             const float* __restrict__ Ebuf,
                                             float* __restrict__ out){
    __shared__ float Es[2048];
    const int bh = blockIdx.y, b = bh >> 4, h = bh & 15;
    const int t0 = blockIdx.x*128;
    for (int i = threadIdx.x; i < 2048; i += 256) Es[i] = Ebuf[(size_t)bh*2048 + i];
    __syncthreads();
    const int t = t0 + (threadIdx.x >> 1);
    const int p0 = (threadIdx.x & 1)*32;
    const float* zq = zqf + ((size_t)b*Tq + t)*512 + h*32;
    float4 z4[8];
#pragma unroll
    for (int q=0;q<8;++q) z4[q] = ((const float4*)zq)[q];
    float* o = out + ((size_t)b*Tq + t)*1024 + h*64 + p0;
#pragma unroll
    for (int pp = 0; pp < 32; pp += 4){
        float4 res;
        float* rp = (float*)&res;
#pragma unroll
        for (int s = 0; s < 4; ++s){
            const float4* er = (const float4*)&Es[(p0 + pp + s)*32];
            float a = 0.f;
#pragma unroll
            for (int q = 0; q < 8; ++q){
                float4 e = er[q];
                a += e.x*z4[q].x + e.y*z4[q].y + e.z*z4[q].z + e.w*z4[q].w;
            }
            rp[s] = a;
        }
        *(float4*)(o + pp) = res;
    }
}

extern "C" void kernel_launch(void* const* d_in, const int* in_sizes, int n_in,
                              void* d_out, int out_size, void* d_ws, size_t ws_size,
                              hipStream_t stream) {
    const float* h    = (const float*)d_in[0];
    const float* mask = (const float*)d_in[1];
    const float* Wk   = (const float*)d_in[2];
    const float* Wq   = (const float*)d_in[3];
    const float* Wv   = (const float*)d_in[4];
    const float* eta  = (const float*)d_in[5];
    const float* gam  = (const float*)d_in[6];
    float* out = (float*)d_out;

    char* ws = (char*)d_ws;
    unsigned short* hbf = (unsigned short*)(ws);                       // 33,554,432
    unsigned short* wbf = (unsigned short*)(ws + 33554432);            //  4,194,304
    unsigned short* zbf = (unsigned short*)(ws + 37748736);            // 16,777,216
    float*          zqf = (float*)         (ws + 54525952);            // 33,554,432
    unsigned short* vbf = (unsigned short*)(ws + 88080384);            // 33,554,432
    unsigned int*   mn  = (unsigned int*)  (ws + 121634816);           //        256
    float*          part= (float*)         (ws + 121635072);           //  8,388,608
    float*          Ebuf= (float*)         (ws + 130023680);           //    524,288

    k_f2bf <<<16384, 256, 0, stream>>>(h, hbf);
    k_wcat <<<2048,  256, 0, stream>>>(Wk, Wq, Wv, wbf);
    k_gemm <<<dim3(16, 128), 256, 0, stream>>>(hbf, wbf, zbf, zqf, vbf);
    k_init <<<1, 64, 0, stream>>>(mn);
    k_norm <<<dim3(8, 64), 256, 0, stream>>>(zbf, mn);
    k_cov  <<<dim3(8, 64), 256, 0, stream>>>(zbf, vbf, mask, part);
    k_solve<<<64,    256, 0, stream>>>(part, (const float*)mn, eta, gam, Ebuf);
    k_out  <<<dim3(32, 64), 256, 0, stream>>>(zqf, Ebuf, out);
}

// Round 3
// 347.606 us; speedup vs baseline: 1.3484x; 1.2075x over previous
//
#include <hip/hip_runtime.h>

#define Tq 4096
#define Dq 1024
#define NCOL 2048      // 512 (z) + 512 (zq) + 1024 (v), all bf16 in one buffer
#define RIDGEC 1e-3f
#define PSTRIDE 4104   // per-(chunk,bh) part slice: 4096 sums + 1 max (+pad)

typedef float  f4_t  __attribute__((ext_vector_type(4)));
typedef __bf16 bf8_t __attribute__((ext_vector_type(8)));
typedef unsigned short us4_t __attribute__((ext_vector_type(4)));

typedef __attribute__((address_space(1))) const void* gas_t;
typedef __attribute__((address_space(3))) void* sas_t;

__device__ __forceinline__ unsigned short f2bf(float f){
    unsigned int u = __float_as_uint(f);
    u += 0x7fffu + ((u >> 16) & 1u);        // RNE
    return (unsigned short)(u >> 16);
}
__device__ __forceinline__ float bf2f(unsigned short u){
    return __uint_as_float(((unsigned int)u) << 16);
}

// ---------------- prep: h -> bf16 (blocks 0..16383), W concat -> bf16 (blocks 16384..18431) ----------------
__global__ __launch_bounds__(256) void k_prep(const float* __restrict__ h,
                                              const float* __restrict__ Wk,
                                              const float* __restrict__ Wq,
                                              const float* __restrict__ Wv,
                                              unsigned short* __restrict__ hbf,
                                              unsigned short* __restrict__ wbf){
    int bx = blockIdx.x;
    if (bx < 16384){
        size_t i = ((size_t)bx*256 + threadIdx.x)*4;
        float4 v = *(const float4*)(h + i);
        us4_t o; o.x=f2bf(v.x); o.y=f2bf(v.y); o.z=f2bf(v.z); o.w=f2bf(v.w);
        *(us4_t*)(hbf + i) = o;
    } else {
        size_t i = ((size_t)(bx - 16384)*256 + threadIdx.x)*4;
        int row = (int)(i >> 10), col = (int)(i & 1023);
        const float* s;
        if (row < 512)       s = Wk + (size_t)row*1024 + col;
        else if (row < 1024) s = Wq + (size_t)(row-512)*1024 + col;
        else                 s = Wv + (size_t)(row-1024)*1024 + col;
        float4 v = *(const float4*)s;
        us4_t o; o.x=f2bf(v.x); o.y=f2bf(v.y); o.z=f2bf(v.z); o.w=f2bf(v.w);
        *(us4_t*)(wbf + i) = o;
    }
}

// ---------------- bf16 MFMA GEMM: zqv(16384x2048 bf16) = h @ W^T ----------------
__global__ __launch_bounds__(256) void k_gemm(const unsigned short* __restrict__ A,
                                              const unsigned short* __restrict__ Bw,
                                              unsigned short* __restrict__ zqv){
    __shared__ __align__(16) unsigned short As[128*32];
    __shared__ __align__(16) unsigned short Bs[128*32];
    const int tid = threadIdx.x, w = tid >> 6, lane = tid & 63;
    const int m0 = blockIdx.y*128, n0 = blockIdx.x*128;
    const int wm = (w >> 1)*64, wn = (w & 1)*64;
    const int row16 = lane & 15, klo = (lane >> 4)*8;

    f4_t acc[4][4];
#pragma unroll
    for (int i=0;i<4;++i)
#pragma unroll
        for (int j=0;j<4;++j) acc[i][j] = (f4_t){0.f,0.f,0.f,0.f};

    for (int k0 = 0; k0 < Dq; k0 += 32){
#pragma unroll
        for (int j=0;j<2;++j){
            int chunk = w*2 + j;
            int e = chunk*512 + lane*8;
            int r = e >> 5, c = e & 31;
            const unsigned short* ga = A  + (size_t)(m0 + r)*Dq + k0 + c;
            const unsigned short* gb = Bw + (size_t)(n0 + r)*Dq + k0 + c;
            __builtin_amdgcn_global_load_lds((gas_t)ga, (sas_t)&As[chunk*512], 16, 0, 0);
            __builtin_amdgcn_global_load_lds((gas_t)gb, (sas_t)&Bs[chunk*512], 16, 0, 0);
        }
        __syncthreads();
        bf8_t aF[4], bF[4];
#pragma unroll
        for (int i=0;i<4;++i) aF[i] = *(const bf8_t*)&As[(wm + i*16 + row16)*32 + klo];
#pragma unroll
        for (int j=0;j<4;++j) bF[j] = *(const bf8_t*)&Bs[(wn + j*16 + row16)*32 + klo];
#pragma unroll
        for (int i=0;i<4;++i)
#pragma unroll
            for (int j=0;j<4;++j)
                acc[i][j] = __builtin_amdgcn_mfma_f32_16x16x32_bf16(aF[i], bF[j], acc[i][j], 0, 0, 0);
        __syncthreads();
    }
#pragma unroll
    for (int i=0;i<4;++i){
#pragma unroll
        for (int j=0;j<4;++j){
            int col = n0 + wn + j*16 + row16;
            int rb  = m0 + wm + i*16 + (lane >> 4)*4;
#pragma unroll
            for (int q=0;q<4;++q)
                zqv[(size_t)(rb+q)*NCOL + col] = f2bf(acc[i][j][q]);
        }
    }
}

// ---------------- G / M_cov / C_v partial sums + per-chunk max||z||^2 ----------------
__global__ __launch_bounds__(256) void k_cov(const unsigned short* __restrict__ zqv,
                                             const float* __restrict__ mask,
                                             float* __restrict__ part){
    __shared__ float Zs[65*32];
    __shared__ float Vs[64*64];
    __shared__ float Msk[66];
    __shared__ float sMx[64];
    const int tid = threadIdx.x, w = tid >> 6, lane = tid & 63;
    const int c = blockIdx.x, bh = blockIdx.y, b = bh >> 4, h = bh & 15;
    const unsigned short* zb = zqv + (size_t)b*Tq*NCOL + h*32;
    const unsigned short* vb = zqv + (size_t)b*Tq*NCOL + 1024 + h*64;
    const float* mb = mask + (size_t)b*Tq;

    const bool isC = lane >= 32;
    const bool isM = (lane >= 16) && (lane < 32);
    const int li = isC ? (lane - 32) : (lane & 15);
    const int i0 = (li >> 2)*8, j0 = (li & 3)*8;
    const float* Xb = isC ? (Vs + i0) : (Zs + 32 + i0);
    const int xst = isC ? 64 : 32;
    const float* Yb = isM ? (Zs + j0) : (Zs + 32 + j0);
    const int slotbase = isC ? (2048 + i0*32 + j0) : ((isM ? 1024 : 0) + i0*32 + j0);

    float acc[8][8];
#pragma unroll
    for (int i=0;i<8;++i)
#pragma unroll
        for (int j=0;j<8;++j) acc[i][j] = 0.f;
    float mxl = 0.f;

    for (int t0 = c*512; t0 < c*512 + 512; t0 += 64){
        __syncthreads();
        for (int i = tid; i < 520; i += 256){
            int r = i >> 3, cc = (i & 7)*4;
            int t = t0 - 1 + r;
            float4 o;
            if (t >= 0){
                us4_t u = *(const us4_t*)(zb + (size_t)t*NCOL + cc);
                o.x = bf2f(u.x); o.y = bf2f(u.y); o.z = bf2f(u.z); o.w = bf2f(u.w);
            } else { o.x=0.f; o.y=0.f; o.z=0.f; o.w=0.f; }
            *(float4*)&Zs[r*32 + cc] = o;
        }
        for (int i = tid; i < 1024; i += 256){
            int rr = i >> 4, cc = (i & 15)*4;
            us4_t u = *(const us4_t*)(vb + (size_t)(t0 + rr)*NCOL + cc);
            float4 o; o.x=bf2f(u.x); o.y=bf2f(u.y); o.z=bf2f(u.z); o.w=bf2f(u.w);
            *(float4*)&Vs[rr*64 + cc] = o;
        }
        if (tid < 65){ int t = t0 - 1 + tid; Msk[tid] = (t >= 0) ? mb[t] : 0.f; }
        __syncthreads();
        if (tid < 64){
            const float4* pr = (const float4*)&Zs[(tid+1)*32];
            float s = 0.f;
#pragma unroll
            for (int q=0;q<8;++q){ float4 v = pr[q]; s += v.x*v.x + v.y*v.y + v.z*v.z + v.w*v.w; }
            mxl = fmaxf(mxl, s);
        }
#pragma unroll 2
        for (int tt = w; tt < 64; tt += 4){
            const float mt = Msk[tt+1], mp = Msk[tt];
            const float m2 = mt*mt, al = mt*mp;
            const float wgt = isM ? (al*al) : m2;
            const float* xp = Xb + tt*xst;
            const float* yp = Yb + tt*32;
            float4 x0 = *(const float4*)xp, x1 = *(const float4*)(xp + 4);
            float4 y0 = *(const float4*)yp, y1 = *(const float4*)(yp + 4);
            float xs[8] = {x0.x*wgt, x0.y*wgt, x0.z*wgt, x0.w*wgt,
                           x1.x*wgt, x1.y*wgt, x1.z*wgt, x1.w*wgt};
            float ys[8] = {y0.x, y0.y, y0.z, y0.w, y1.x, y1.y, y1.z, y1.w};
#pragma unroll
            for (int i=0;i<8;++i)
#pragma unroll
                for (int j=0;j<8;++j) acc[i][j] += xs[i]*ys[j];
        }
    }
    // cross-wave reduce in LDS (reuse Vs: 4096 floats)
    float* Acc = Vs;
    __syncthreads();
    if (tid < 64) sMx[tid] = mxl;
#pragma unroll
    for (int r = 0; r < 4; ++r){
        if (w == r){
            if (r == 0){
#pragma unroll
                for (int i=0;i<8;++i)
#pragma unroll
                    for (int j=0;j<8;++j) Acc[slotbase + i*32 + j] = acc[i][j];
            } else {
#pragma unroll
                for (int i=0;i<8;++i)
#pragma unroll
                    for (int j=0;j<8;++j) Acc[slotbase + i*32 + j] += acc[i][j];
            }
        }
        __syncthreads();
    }
    float* dst = part + ((size_t)c*64 + bh)*PSTRIDE;
    for (int i = tid; i < 4096; i += 256) dst[i] = Acc[i];
    if (tid == 0){
        float m = 0.f;
#pragma unroll
        for (int q=0;q<64;++q) m = fmaxf(m, sMx[q]);
        dst[4096] = m;
    }
}

// ---------------- per-(b,h) fp32 solver (no Cholesky):
// Gi = G^-1 (Gauss-Jordan), P = M Gi, Q = Gi P, sigma^2 = lam_max(M^T Q) via power iter,
// E = eta/mn * s^2 * C (Q P),  s = gam/max(sigma,1) ----------------
__global__ __launch_bounds__(256) void k_solve(const float* __restrict__ part,
                                               const float* __restrict__ eta_p,
                                               const float* __restrict__ gam_p,
                                               float* __restrict__ Ebuf){
    __shared__ float sM[1024], sC[2048], sGi[1024], sP[1024], sQ[1024], sT[1024];
    __shared__ float sAug[32*66];
    __shared__ float sv[32], su[32], sw[32], ssc[4];
    const int tid = threadIdx.x, bh = blockIdx.x;
    const size_t pb = (size_t)bh*PSTRIDE;

    // max over chunk maxes (redundant per-thread, broadcast loads)
    float mxx = 0.f;
#pragma unroll
    for (int c = 0; c < 8; ++c) mxx = fmaxf(mxx, part[((size_t)c*64)*PSTRIDE + pb + 4096]);
    const float mn = fmaxf(sqrtf(mxx), 1e-6f);
    const float i1 = 1.f/mn, i2 = i1*i1;

    for (int i = tid; i < 1024; i += 256){
        float a0 = 0.f, a1 = 0.f;
        for (int c = 0; c < 8; ++c){
            const float* p = part + ((size_t)c*64)*PSTRIDE + pb;
            a0 += p[i]; a1 += p[1024 + i];
        }
        sT[i] = a0; sM[i] = a1*i2;
    }
    for (int i = tid; i < 2048; i += 256){
        float a = 0.f;
        for (int c = 0; c < 8; ++c) a += part[((size_t)c*64)*PSTRIDE + pb + 2048 + i];
        sC[i] = a*i1;
    }
    __syncthreads();
    // Aug = [G_sym + ridge | I]
    for (int i = tid; i < 1024; i += 256){
        int r = i >> 5, s = i & 31;
        float g = 0.5f*(sT[i] + sT[s*32 + r])*i2 + (r == s ? RIDGEC : 0.f);
        sAug[r*66 + s] = g;
        sAug[r*66 + 32 + s] = (r == s) ? 1.f : 0.f;
    }
    __syncthreads();
    // Gauss-Jordan (SPD, no pivoting)
    const int gi = tid >> 3, gj0 = (tid & 7)*8;
    for (int p = 0; p < 32; ++p){
        float pivd = sAug[p*66 + p];
        float f    = sAug[gi*66 + p];
        float rp[8];
#pragma unroll
        for (int jj = 0; jj < 8; ++jj) rp[jj] = sAug[p*66 + gj0 + jj];
        __syncthreads();
        float pinv = 1.f/pivd;
        if (gi == p){
#pragma unroll
            for (int jj = 0; jj < 8; ++jj) sAug[p*66 + gj0 + jj] = rp[jj]*pinv;
        } else {
            float fp = f*pinv;
#pragma unroll
            for (int jj = 0; jj < 8; ++jj) sAug[gi*66 + gj0 + jj] -= fp*rp[jj];
        }
        __syncthreads();
    }
    for (int i = tid; i < 1024; i += 256){
        int r = i >> 5, s = i & 31;
        sGi[i] = sAug[r*66 + 32 + s];
    }
    __syncthreads();
    // P = M @ Gi   (left-row preload, float4 broadcast on right)
    {
        const int r = tid >> 3, s0 = (tid & 7)*4;
        float lrow[32];
#pragma unroll
        for (int q = 0; q < 8; ++q) *(float4*)&lrow[q*4] = *(const float4*)&sM[r*32 + q*4];
        float4 a = (float4){0.f,0.f,0.f,0.f};
        for (int k = 0; k < 32; ++k){
            float4 bb = *(const float4*)&sGi[k*32 + s0];
            a.x += lrow[k]*bb.x; a.y += lrow[k]*bb.y; a.z += lrow[k]*bb.z; a.w += lrow[k]*bb.w;
        }
        *(float4*)&sP[r*32 + s0] = a;
    }
    __syncthreads();
    // Q = Gi @ P
    {
        const int r = tid >> 3, s0 = (tid & 7)*4;
        float lrow[32];
#pragma unroll
        for (int q = 0; q < 8; ++q) *(float4*)&lrow[q*4] = *(const float4*)&sGi[r*32 + q*4];
        float4 a = (float4){0.f,0.f,0.f,0.f};
        for (int k = 0; k < 32; ++k){
            float4 bb = *(const float4*)&sP[k*32 + s0];
            a.x += lrow[k]*bb.x; a.y += lrow[k]*bb.y; a.z += lrow[k]*bb.z; a.w += lrow[k]*bb.w;
        }
        *(float4*)&sQ[r*32 + s0] = a;
    }
    __syncthreads();
    // power iteration: v <- normalize(M^T (Q v)), 6 iters; then lam = ||M^T Q v||, sigma = lam^0.5
    if (tid < 32) sv[tid] = 0.17677669529663687f;
    __syncthreads();
    for (int it = 0; it < 6; ++it){
        if (tid < 32){ float a = 0.f; for (int k = 0; k < 32; ++k) a += sQ[tid*32+k]*sv[k]; su[tid] = a; }
        __syncthreads();
        if (tid < 32){ float a = 0.f; for (int k = 0; k < 32; ++k) a += sM[k*32+tid]*su[k]; sw[tid] = a; }
        __syncthreads();
        if (tid < 32){
            float n2 = 0.f;
#pragma unroll
            for (int k = 0; k < 32; ++k) n2 += sw[k]*sw[k];
            sv[tid] = sw[tid] * (1.f/fmaxf(sqrtf(n2), 1e-8f));
        }
        __syncthreads();
    }
    if (tid < 32){ float a = 0.f; for (int k = 0; k < 32; ++k) a += sQ[tid*32+k]*sv[k]; su[tid] = a; }
    __syncthreads();
    if (tid < 32){ float a = 0.f; for (int k = 0; k < 32; ++k) a += sM[k*32+tid]*su[k]; sw[tid] = a; }
    __syncthreads();
    if (tid == 0){
        float n2 = 0.f;
        for (int k = 0; k < 32; ++k) n2 += sw[k]*sw[k];
        float sigma = sqrtf(sqrtf(n2));          // ||Wv|| = sigma^2
        float gam = fminf(fmaxf(gam_p[0], 1.f), 1.5f);
        float s = gam/fmaxf(sigma, 1.f);
        ssc[0] = eta_p[0]*i1*s*s;
    }
    __syncthreads();
    // T = Q @ P
    {
        const int r = tid >> 3, s0 = (tid & 7)*4;
        float lrow[32];
#pragma unroll
        for (int q = 0; q < 8; ++q) *(float4*)&lrow[q*4] = *(const float4*)&sQ[r*32 + q*4];
        float4 a = (float4){0.f,0.f,0.f,0.f};
        for (int k = 0; k < 32; ++k){
            float4 bb = *(const float4*)&sP[k*32 + s0];
            a.x += lrow[k]*bb.x; a.y += lrow[k]*bb.y; a.z += lrow[k]*bb.z; a.w += lrow[k]*bb.w;
        }
        *(float4*)&sT[r*32 + s0] = a;
    }
    __syncthreads();
    // E = esc * C @ T  (64x32 @ 32x32)
    {
        const float esc = ssc[0];
        const int r = tid >> 2, s0 = (tid & 3)*8;
        float lrow[32];
#pragma unroll
        for (int q = 0; q < 8; ++q) *(float4*)&lrow[q*4] = *(const float4*)&sC[r*32 + q*4];
        float4 a0 = (float4){0.f,0.f,0.f,0.f}, a1 = (float4){0.f,0.f,0.f,0.f};
        for (int k = 0; k < 32; ++k){
            float4 b0 = *(const float4*)&sT[k*32 + s0];
            float4 b1 = *(const float4*)&sT[k*32 + s0 + 4];
            a0.x += lrow[k]*b0.x; a0.y += lrow[k]*b0.y; a0.z += lrow[k]*b0.z; a0.w += lrow[k]*b0.w;
            a1.x += lrow[k]*b1.x; a1.y += lrow[k]*b1.y; a1.z += lrow[k]*b1.z; a1.w += lrow[k]*b1.w;
        }
        a0.x*=esc; a0.y*=esc; a0.z*=esc; a0.w*=esc;
        a1.x*=esc; a1.y*=esc; a1.z*=esc; a1.w*=esc;
        *(float4*)&Ebuf[(size_t)bh*2048 + r*32 + s0]     = a0;
        *(float4*)&Ebuf[(size_t)bh*2048 + r*32 + s0 + 4] = a1;
    }
}

// ---------------- out[b,t,h,:] = E[b,h] @ zq_f[b,t,h,:] ----------------
__global__ __launch_bounds__(256) void k_out(const unsigned short* __restrict__ zqv,
                                             const float* __restrict__ Ebuf,
                                             float* __restrict__ out){
    __shared__ float Es[2048];
    const int bh = blockIdx.y, b = bh >> 4, h = bh & 15;
    const int t0 = blockIdx.x*128;
    for (int i = threadIdx.x; i < 2048; i += 256) Es[i] = Ebuf[(size_t)bh*2048 + i];
    __syncthreads();
    const int t = t0 + (threadIdx.x >> 1);
    const int p0 = (threadIdx.x & 1)*32;
    const unsigned short* zq = zqv + ((size_t)b*Tq + t)*NCOL + 512 + h*32;
    float4 z4[8];
#pragma unroll
    for (int q=0;q<8;++q){
        us4_t u = ((const us4_t*)zq)[q];
        z4[q].x = bf2f(u.x); z4[q].y = bf2f(u.y); z4[q].z = bf2f(u.z); z4[q].w = bf2f(u.w);
    }
    float* o = out + ((size_t)b*Tq + t)*1024 + h*64 + p0;
#pragma unroll
    for (int pp = 0; pp < 32; pp += 4){
        float4 res;
        float* rp = (float*)&res;
#pragma unroll
        for (int s = 0; s < 4; ++s){
            const float4* er = (const float4*)&Es[(p0 + pp + s)*32];
            float a = 0.f;
#pragma unroll
            for (int q = 0; q < 8; ++q){
                float4 e = er[q];
                a += e.x*z4[q].x + e.y*z4[q].y + e.z*z4[q].z + e.w*z4[q].w;
            }
            rp[s] = a;
        }
        *(float4*)(o + pp) = res;
    }
}

extern "C" void kernel_launch(void* const* d_in, const int* in_sizes, int n_in,
                              void* d_out, int out_size, void* d_ws, size_t ws_size,
                              hipStream_t stream) {
    const float* h    = (const float*)d_in[0];
    const float* mask = (const float*)d_in[1];
    const float* Wk   = (const float*)d_in[2];
    const float* Wq   = (const float*)d_in[3];
    const float* Wv   = (const float*)d_in[4];
    const float* eta  = (const float*)d_in[5];
    const float* gam  = (const float*)d_in[6];
    float* out = (float*)d_out;

    char* ws = (char*)d_ws;
    unsigned short* hbf = (unsigned short*)(ws);                       // 33,554,432
    unsigned short* wbf = (unsigned short*)(ws + 33554432);            //  4,194,304
    unsigned short* zqv = (unsigned short*)(ws + 37748736);            // 67,108,864
    float*          part= (float*)         (ws + 104857600);           //  8,404,992
    float*          Ebuf= (float*)         (ws + 113262592);           //    524,288

    k_prep <<<18432, 256, 0, stream>>>(h, Wk, Wq, Wv, hbf, wbf);
    k_gemm <<<dim3(16, 128), 256, 0, stream>>>(hbf, wbf, zqv);
    k_cov  <<<dim3(8, 64), 256, 0, stream>>>(zqv, mask, part);
    k_solve<<<64, 256, 0, stream>>>(part, eta, gam, Ebuf);
    k_out  <<<dim3(32, 64), 256, 0, stream>>>(zqv, Ebuf, out);
}

// Round 4
// 310.143 us; speedup vs baseline: 1.5113x; 1.1208x over previous
//
#include <hip/hip_runtime.h>

#define Tq 4096
#define Dq 1024
#define NCOL 2048      // 512 (z) + 512 (zq) + 1024 (v), all bf16 in one buffer
#define RIDGEC 1e-3f
#define PSTRIDE 4104   // per-(chunk,bh) part slice: 4096 sums + 1 max (+pad)

typedef float  f4_t  __attribute__((ext_vector_type(4)));
typedef __bf16 bf8_t __attribute__((ext_vector_type(8)));
typedef unsigned short us4_t __attribute__((ext_vector_type(4)));

typedef __attribute__((address_space(1))) const void* gas_t;
typedef __attribute__((address_space(3))) void* sas_t;

__device__ __forceinline__ unsigned short f2bf(float f){
    unsigned int u = __float_as_uint(f);
    u += 0x7fffu + ((u >> 16) & 1u);        // RNE
    return (unsigned short)(u >> 16);
}
__device__ __forceinline__ float bf2f(unsigned short u){
    return __uint_as_float(((unsigned int)u) << 16);
}

// ---------------- prep: h -> bf16 (blocks 0..16383), W concat -> bf16 (blocks 16384..18431) ----------------
__global__ __launch_bounds__(256) void k_prep(const float* __restrict__ h,
                                              const float* __restrict__ Wk,
                                              const float* __restrict__ Wq,
                                              const float* __restrict__ Wv,
                                              unsigned short* __restrict__ hbf,
                                              unsigned short* __restrict__ wbf){
    int bx = blockIdx.x;
    if (bx < 16384){
        size_t i = ((size_t)bx*256 + threadIdx.x)*4;
        float4 v = *(const float4*)(h + i);
        us4_t o; o.x=f2bf(v.x); o.y=f2bf(v.y); o.z=f2bf(v.z); o.w=f2bf(v.w);
        *(us4_t*)(hbf + i) = o;
    } else {
        size_t i = ((size_t)(bx - 16384)*256 + threadIdx.x)*4;
        int row = (int)(i >> 10), col = (int)(i & 1023);
        const float* s;
        if (row < 512)       s = Wk + (size_t)row*1024 + col;
        else if (row < 1024) s = Wq + (size_t)(row-512)*1024 + col;
        else                 s = Wv + (size_t)(row-1024)*1024 + col;
        float4 v = *(const float4*)s;
        us4_t o; o.x=f2bf(v.x); o.y=f2bf(v.y); o.z=f2bf(v.z); o.w=f2bf(v.w);
        *(us4_t*)(wbf + i) = o;
    }
}

// ---------------- bf16 MFMA GEMM: zqv(16384x2048 bf16) = h @ W^T ----------------
__global__ __launch_bounds__(256) void k_gemm(const unsigned short* __restrict__ A,
                                              const unsigned short* __restrict__ Bw,
                                              unsigned short* __restrict__ zqv){
    __shared__ __align__(16) unsigned short As[128*32];
    __shared__ __align__(16) unsigned short Bs[128*32];
    const int tid = threadIdx.x, w = tid >> 6, lane = tid & 63;
    const int m0 = blockIdx.y*128, n0 = blockIdx.x*128;
    const int wm = (w >> 1)*64, wn = (w & 1)*64;
    const int row16 = lane & 15, klo = (lane >> 4)*8;

    f4_t acc[4][4];
#pragma unroll
    for (int i=0;i<4;++i)
#pragma unroll
        for (int j=0;j<4;++j) acc[i][j] = (f4_t){0.f,0.f,0.f,0.f};

    for (int k0 = 0; k0 < Dq; k0 += 32){
#pragma unroll
        for (int j=0;j<2;++j){
            int chunk = w*2 + j;
            int e = chunk*512 + lane*8;
            int r = e >> 5, c = e & 31;
            const unsigned short* ga = A  + (size_t)(m0 + r)*Dq + k0 + c;
            const unsigned short* gb = Bw + (size_t)(n0 + r)*Dq + k0 + c;
            __builtin_amdgcn_global_load_lds((gas_t)ga, (sas_t)&As[chunk*512], 16, 0, 0);
            __builtin_amdgcn_global_load_lds((gas_t)gb, (sas_t)&Bs[chunk*512], 16, 0, 0);
        }
        __syncthreads();
        bf8_t aF[4], bF[4];
#pragma unroll
        for (int i=0;i<4;++i) aF[i] = *(const bf8_t*)&As[(wm + i*16 + row16)*32 + klo];
#pragma unroll
        for (int j=0;j<4;++j) bF[j] = *(const bf8_t*)&Bs[(wn + j*16 + row16)*32 + klo];
#pragma unroll
        for (int i=0;i<4;++i)
#pragma unroll
            for (int j=0;j<4;++j)
                acc[i][j] = __builtin_amdgcn_mfma_f32_16x16x32_bf16(aF[i], bF[j], acc[i][j], 0, 0, 0);
        __syncthreads();
    }
#pragma unroll
    for (int i=0;i<4;++i){
#pragma unroll
        for (int j=0;j<4;++j){
            int col = n0 + wn + j*16 + row16;
            int rb  = m0 + wm + i*16 + (lane >> 4)*4;
#pragma unroll
            for (int q=0;q<4;++q)
                zqv[(size_t)(rb+q)*NCOL + col] = f2bf(acc[i][j][q]);
        }
    }
}

// ---------------- G / M_cov / C_v partial sums + per-chunk max||z||^2 ----------------
__global__ __launch_bounds__(256) void k_cov(const unsigned short* __restrict__ zqv,
                                             const float* __restrict__ mask,
                                             float* __restrict__ part){
    __shared__ float Zs[65*32];
    __shared__ float Vs[64*64];
    __shared__ float Msk[66];
    __shared__ float sMx[64];
    const int tid = threadIdx.x, w = tid >> 6, lane = tid & 63;
    const int c = blockIdx.x, bh = blockIdx.y, b = bh >> 4, h = bh & 15;
    const unsigned short* zb = zqv + (size_t)b*Tq*NCOL + h*32;
    const unsigned short* vb = zqv + (size_t)b*Tq*NCOL + 1024 + h*64;
    const float* mb = mask + (size_t)b*Tq;

    const bool isC = lane >= 32;
    const bool isM = (lane >= 16) && (lane < 32);
    const int li = isC ? (lane - 32) : (lane & 15);
    const int i0 = (li >> 2)*8, j0 = (li & 3)*8;
    const float* Xb = isC ? (Vs + i0) : (Zs + 32 + i0);
    const int xst = isC ? 64 : 32;
    const float* Yb = isM ? (Zs + j0) : (Zs + 32 + j0);
    const int slotbase = isC ? (2048 + i0*32 + j0) : ((isM ? 1024 : 0) + i0*32 + j0);

    float acc[8][8];
#pragma unroll
    for (int i=0;i<8;++i)
#pragma unroll
        for (int j=0;j<8;++j) acc[i][j] = 0.f;
    float mxl = 0.f;

    for (int t0 = c*512; t0 < c*512 + 512; t0 += 64){
        __syncthreads();
        for (int i = tid; i < 520; i += 256){
            int r = i >> 3, cc = (i & 7)*4;
            int t = t0 - 1 + r;
            float4 o;
            if (t >= 0){
                us4_t u = *(const us4_t*)(zb + (size_t)t*NCOL + cc);
                o.x = bf2f(u.x); o.y = bf2f(u.y); o.z = bf2f(u.z); o.w = bf2f(u.w);
            } else { o.x=0.f; o.y=0.f; o.z=0.f; o.w=0.f; }
            *(float4*)&Zs[r*32 + cc] = o;
        }
        for (int i = tid; i < 1024; i += 256){
            int rr = i >> 4, cc = (i & 15)*4;
            us4_t u = *(const us4_t*)(vb + (size_t)(t0 + rr)*NCOL + cc);
            float4 o; o.x=bf2f(u.x); o.y=bf2f(u.y); o.z=bf2f(u.z); o.w=bf2f(u.w);
            *(float4*)&Vs[rr*64 + cc] = o;
        }
        if (tid < 65){ int t = t0 - 1 + tid; Msk[tid] = (t >= 0) ? mb[t] : 0.f; }
        __syncthreads();
        if (tid < 64){
            const float4* pr = (const float4*)&Zs[(tid+1)*32];
            float s = 0.f;
#pragma unroll
            for (int q=0;q<8;++q){ float4 v = pr[q]; s += v.x*v.x + v.y*v.y + v.z*v.z + v.w*v.w; }
            mxl = fmaxf(mxl, s);
        }
#pragma unroll 2
        for (int tt = w; tt < 64; tt += 4){
            const float mt = Msk[tt+1], mp = Msk[tt];
            const float m2 = mt*mt, al = mt*mp;
            const float wgt = isM ? (al*al) : m2;
            const float* xp = Xb + tt*xst;
            const float* yp = Yb + tt*32;
            float4 x0 = *(const float4*)xp, x1 = *(const float4*)(xp + 4);
            float4 y0 = *(const float4*)yp, y1 = *(const float4*)(yp + 4);
            float xs[8] = {x0.x*wgt, x0.y*wgt, x0.z*wgt, x0.w*wgt,
                           x1.x*wgt, x1.y*wgt, x1.z*wgt, x1.w*wgt};
            float ys[8] = {y0.x, y0.y, y0.z, y0.w, y1.x, y1.y, y1.z, y1.w};
#pragma unroll
            for (int i=0;i<8;++i)
#pragma unroll
                for (int j=0;j<8;++j) acc[i][j] += xs[i]*ys[j];
        }
    }
    // cross-wave reduce in LDS (reuse Vs: 4096 floats)
    float* Acc = Vs;
    __syncthreads();
    if (tid < 64) sMx[tid] = mxl;
#pragma unroll
    for (int r = 0; r < 4; ++r){
        if (w == r){
            if (r == 0){
#pragma unroll
                for (int i=0;i<8;++i)
#pragma unroll
                    for (int j=0;j<8;++j) Acc[slotbase + i*32 + j] = acc[i][j];
            } else {
#pragma unroll
                for (int i=0;i<8;++i)
#pragma unroll
                    for (int j=0;j<8;++j) Acc[slotbase + i*32 + j] += acc[i][j];
            }
        }
        __syncthreads();
    }
    float* dst = part + ((size_t)c*64 + bh)*PSTRIDE;
    for (int i = tid; i < 4096; i += 256) dst[i] = Acc[i];
    if (tid == 0){
        float m = 0.f;
#pragma unroll
        for (int q=0;q<64;++q) m = fmaxf(m, sMx[q]);
        dst[4096] = m;
    }
}

// ---------------- per-(b,h) fp32 solver (no Cholesky):
// Gi = G^-1 (Gauss-Jordan), P = M Gi, Q = Gi P, sigma^2 = lam_max(M^T Q) via power iter,
// E = eta/mn * s^2 * C (Q P),  s = gam/max(sigma,1); E stored bf16 ----------------
__global__ __launch_bounds__(256) void k_solve(const float* __restrict__ part,
                                               const float* __restrict__ eta_p,
                                               const float* __restrict__ gam_p,
                                               unsigned short* __restrict__ Ebf){
    __shared__ float sM[1024], sC[2048], sGi[1024], sP[1024], sQ[1024], sT[1024];
    __shared__ float sAug[32*66];
    __shared__ float sv[32], su[32], sw[32], ssc[4];
    const int tid = threadIdx.x, bh = blockIdx.x;
    const size_t pb = (size_t)bh*PSTRIDE;

    // max over chunk maxes (redundant per-thread, broadcast loads)
    float mxx = 0.f;
#pragma unroll
    for (int c = 0; c < 8; ++c) mxx = fmaxf(mxx, part[((size_t)c*64)*PSTRIDE + pb + 4096]);
    const float mn = fmaxf(sqrtf(mxx), 1e-6f);
    const float i1 = 1.f/mn, i2 = i1*i1;

    for (int i = tid; i < 1024; i += 256){
        float a0 = 0.f, a1 = 0.f;
        for (int c = 0; c < 8; ++c){
            const float* p = part + ((size_t)c*64)*PSTRIDE + pb;
            a0 += p[i]; a1 += p[1024 + i];
        }
        sT[i] = a0; sM[i] = a1*i2;
    }
    for (int i = tid; i < 2048; i += 256){
        float a = 0.f;
        for (int c = 0; c < 8; ++c) a += part[((size_t)c*64)*PSTRIDE + pb + 2048 + i];
        sC[i] = a*i1;
    }
    __syncthreads();
    // Aug = [G_sym + ridge | I]
    for (int i = tid; i < 1024; i += 256){
        int r = i >> 5, s = i & 31;
        float g = 0.5f*(sT[i] + sT[s*32 + r])*i2 + (r == s ? RIDGEC : 0.f);
        sAug[r*66 + s] = g;
        sAug[r*66 + 32 + s] = (r == s) ? 1.f : 0.f;
    }
    __syncthreads();
    // Gauss-Jordan (SPD, no pivoting)
    const int gi = tid >> 3, gj0 = (tid & 7)*8;
    for (int p = 0; p < 32; ++p){
        float pivd = sAug[p*66 + p];
        float f    = sAug[gi*66 + p];
        float rp[8];
#pragma unroll
        for (int jj = 0; jj < 8; ++jj) rp[jj] = sAug[p*66 + gj0 + jj];
        __syncthreads();
        float pinv = 1.f/pivd;
        if (gi == p){
#pragma unroll
            for (int jj = 0; jj < 8; ++jj) sAug[p*66 + gj0 + jj] = rp[jj]*pinv;
        } else {
            float fp = f*pinv;
#pragma unroll
            for (int jj = 0; jj < 8; ++jj) sAug[gi*66 + gj0 + jj] -= fp*rp[jj];
        }
        __syncthreads();
    }
    for (int i = tid; i < 1024; i += 256){
        int r = i >> 5, s = i & 31;
        sGi[i] = sAug[r*66 + 32 + s];
    }
    __syncthreads();
    // P = M @ Gi   (left-row preload, float4 broadcast on right)
    {
        const int r = tid >> 3, s0 = (tid & 7)*4;
        float lrow[32];
#pragma unroll
        for (int q = 0; q < 8; ++q) *(float4*)&lrow[q*4] = *(const float4*)&sM[r*32 + q*4];
        float4 a = (float4){0.f,0.f,0.f,0.f};
        for (int k = 0; k < 32; ++k){
            float4 bb = *(const float4*)&sGi[k*32 + s0];
            a.x += lrow[k]*bb.x; a.y += lrow[k]*bb.y; a.z += lrow[k]*bb.z; a.w += lrow[k]*bb.w;
        }
        *(float4*)&sP[r*32 + s0] = a;
    }
    __syncthreads();
    // Q = Gi @ P
    {
        const int r = tid >> 3, s0 = (tid & 7)*4;
        float lrow[32];
#pragma unroll
        for (int q = 0; q < 8; ++q) *(float4*)&lrow[q*4] = *(const float4*)&sGi[r*32 + q*4];
        float4 a = (float4){0.f,0.f,0.f,0.f};
        for (int k = 0; k < 32; ++k){
            float4 bb = *(const float4*)&sP[k*32 + s0];
            a.x += lrow[k]*bb.x; a.y += lrow[k]*bb.y; a.z += lrow[k]*bb.z; a.w += lrow[k]*bb.w;
        }
        *(float4*)&sQ[r*32 + s0] = a;
    }
    __syncthreads();
    // power iteration: v <- normalize(M^T (Q v)), 6 iters
    if (tid < 32) sv[tid] = 0.17677669529663687f;
    __syncthreads();
    for (int it = 0; it < 6; ++it){
        if (tid < 32){ float a = 0.f; for (int k = 0; k < 32; ++k) a += sQ[tid*32+k]*sv[k]; su[tid] = a; }
        __syncthreads();
        if (tid < 32){ float a = 0.f; for (int k = 0; k < 32; ++k) a += sM[k*32+tid]*su[k]; sw[tid] = a; }
        __syncthreads();
        if (tid < 32){
            float n2 = 0.f;
#pragma unroll
            for (int k = 0; k < 32; ++k) n2 += sw[k]*sw[k];
            sv[tid] = sw[tid] * (1.f/fmaxf(sqrtf(n2), 1e-8f));
        }
        __syncthreads();
    }
    if (tid < 32){ float a = 0.f; for (int k = 0; k < 32; ++k) a += sQ[tid*32+k]*sv[k]; su[tid] = a; }
    __syncthreads();
    if (tid < 32){ float a = 0.f; for (int k = 0; k < 32; ++k) a += sM[k*32+tid]*su[k]; sw[tid] = a; }
    __syncthreads();
    if (tid == 0){
        float n2 = 0.f;
        for (int k = 0; k < 32; ++k) n2 += sw[k]*sw[k];
        float sigma = sqrtf(sqrtf(n2));          // ||Wv|| = sigma^2
        float gam = fminf(fmaxf(gam_p[0], 1.f), 1.5f);
        float s = gam/fmaxf(sigma, 1.f);
        ssc[0] = eta_p[0]*i1*s*s;
    }
    __syncthreads();
    // T = Q @ P
    {
        const int r = tid >> 3, s0 = (tid & 7)*4;
        float lrow[32];
#pragma unroll
        for (int q = 0; q < 8; ++q) *(float4*)&lrow[q*4] = *(const float4*)&sQ[r*32 + q*4];
        float4 a = (float4){0.f,0.f,0.f,0.f};
        for (int k = 0; k < 32; ++k){
            float4 bb = *(const float4*)&sP[k*32 + s0];
            a.x += lrow[k]*bb.x; a.y += lrow[k]*bb.y; a.z += lrow[k]*bb.z; a.w += lrow[k]*bb.w;
        }
        *(float4*)&sT[r*32 + s0] = a;
    }
    __syncthreads();
    // E = esc * C @ T  (64x32 @ 32x32), stored bf16 row-major (p x r)
    {
        const float esc = ssc[0];
        const int r = tid >> 2, s0 = (tid & 3)*8;
        float lrow[32];
#pragma unroll
        for (int q = 0; q < 8; ++q) *(float4*)&lrow[q*4] = *(const float4*)&sC[r*32 + q*4];
        float4 a0 = (float4){0.f,0.f,0.f,0.f}, a1 = (float4){0.f,0.f,0.f,0.f};
        for (int k = 0; k < 32; ++k){
            float4 b0 = *(const float4*)&sT[k*32 + s0];
            float4 b1 = *(const float4*)&sT[k*32 + s0 + 4];
            a0.x += lrow[k]*b0.x; a0.y += lrow[k]*b0.y; a0.z += lrow[k]*b0.z; a0.w += lrow[k]*b0.w;
            a1.x += lrow[k]*b1.x; a1.y += lrow[k]*b1.y; a1.z += lrow[k]*b1.z; a1.w += lrow[k]*b1.w;
        }
        us4_t o0, o1;
        o0.x=f2bf(a0.x*esc); o0.y=f2bf(a0.y*esc); o0.z=f2bf(a0.z*esc); o0.w=f2bf(a0.w*esc);
        o1.x=f2bf(a1.x*esc); o1.y=f2bf(a1.y*esc); o1.z=f2bf(a1.z*esc); o1.w=f2bf(a1.w*esc);
        *(us4_t*)&Ebf[(size_t)bh*2048 + r*32 + s0]     = o0;
        *(us4_t*)&Ebf[(size_t)bh*2048 + r*32 + s0 + 4] = o1;
    }
}

// ---------------- out[t,p] = sum_r zq[t,r] * E[p,r]  via MFMA (A=zq rows, B=E rows) ----------------
__global__ __launch_bounds__(256) void k_outm(const unsigned short* __restrict__ zqv,
                                              const unsigned short* __restrict__ Ebf,
                                              float* __restrict__ out){
    __shared__ __align__(16) unsigned short Es[2048];
    const int tid = threadIdx.x, w = tid >> 6, lane = tid & 63;
    const int bh = blockIdx.y, b = bh >> 4, h = bh & 15;
    // stage E (64 p x 32 r bf16 = 4096 B)
    ((float4*)Es)[tid & 255] = ((const float4*)(Ebf + (size_t)bh*2048))[tid & 255];
    __syncthreads();

    const int row16 = lane & 15, klo = (lane >> 4)*8;
    const int t0 = blockIdx.x*128 + w*32;
    const unsigned short* zq = zqv + ((size_t)b*Tq + t0 + row16)*NCOL + 512 + h*32 + klo;
    bf8_t aF0 = *(const bf8_t*)zq;
    bf8_t aF1 = *(const bf8_t*)(zq + (size_t)16*NCOL);

    bf8_t bF[4];
#pragma unroll
    for (int j=0;j<4;++j) bF[j] = *(const bf8_t*)&Es[(j*16 + row16)*32 + klo];

    f4_t acc[2][4];
#pragma unroll
    for (int i=0;i<2;++i)
#pragma unroll
        for (int j=0;j<4;++j) acc[i][j] = (f4_t){0.f,0.f,0.f,0.f};
#pragma unroll
    for (int j=0;j<4;++j){
        acc[0][j] = __builtin_amdgcn_mfma_f32_16x16x32_bf16(aF0, bF[j], acc[0][j], 0, 0, 0);
        acc[1][j] = __builtin_amdgcn_mfma_f32_16x16x32_bf16(aF1, bF[j], acc[1][j], 0, 0, 0);
    }
    const int rbase = (lane >> 4)*4;
#pragma unroll
    for (int half=0; half<2; ++half){
#pragma unroll
        for (int j=0;j<4;++j){
            int col = h*64 + j*16 + row16;
#pragma unroll
            for (int q=0;q<4;++q){
                int t = t0 + half*16 + rbase + q;
                out[((size_t)b*Tq + t)*1024 + col] = acc[half][j][q];
            }
        }
    }
}

extern "C" void kernel_launch(void* const* d_in, const int* in_sizes, int n_in,
                              void* d_out, int out_size, void* d_ws, size_t ws_size,
                              hipStream_t stream) {
    const float* h    = (const float*)d_in[0];
    const float* mask = (const float*)d_in[1];
    const float* Wk   = (const float*)d_in[2];
    const float* Wq   = (const float*)d_in[3];
    const float* Wv   = (const float*)d_in[4];
    const float* eta  = (const float*)d_in[5];
    const float* gam  = (const float*)d_in[6];
    float* out = (float*)d_out;

    char* ws = (char*)d_ws;
    unsigned short* hbf = (unsigned short*)(ws);                       // 33,554,432
    unsigned short* wbf = (unsigned short*)(ws + 33554432);            //  4,194,304
    unsigned short* zqv = (unsigned short*)(ws + 37748736);            // 67,108,864
    float*          part= (float*)         (ws + 104857600);           //  8,404,992
    unsigned short* Ebf = (unsigned short*)(ws + 113262592);           //    262,144

    k_prep <<<18432, 256, 0, stream>>>(h, Wk, Wq, Wv, hbf, wbf);
    k_gemm <<<dim3(16, 128), 256, 0, stream>>>(hbf, wbf, zqv);
    k_cov  <<<dim3(8, 64), 256, 0, stream>>>(zqv, mask, part);
    k_solve<<<64, 256, 0, stream>>>(part, eta, gam, Ebf);
    k_outm <<<dim3(32, 64), 256, 0, stream>>>(zqv, Ebf, out);
}